// Round 1
// baseline (571.254 us; speedup 1.0000x reference)
//
#include <hip/hip_runtime.h>

// HMM forward scan, one workgroup per unit u.
//   U=256 units, N=64 states, S=4 symbols, B=64 batch, T=1024 steps.
// Wave w (of 4) owns batches b in [16w,16w+16).
// Per step: D[j][b] = sum_i A[i][j]*alpha[b][i] via bf16 MFMA 16x16x32
// (m=j tile x4, n=b=wave's 16 batches, K=64 -> 2 mfma per tile).
// E (emission dot, K=4) kept in fp32 VALU; log/normalize fp32.
// alpha converts C-layout -> B-operand layout via a wave-private LDS slice.

#define U_ 256
#define N_ 64
#define S_ 4
#define B_ 64
#define T_ 1024
#define ROWP 72  // LDS row stride in bf16 elems (144 B): conflict-free, 16B-aligned

typedef __attribute__((ext_vector_type(8))) __bf16 bf16x8;
typedef __attribute__((ext_vector_type(4))) __bf16 bf16x4;
typedef __attribute__((ext_vector_type(4))) float floatx4;

__launch_bounds__(256, 1)
__global__ void hmm_fwd_kernel(const float* __restrict__ xg,     // [B][T][S]
                               const float* __restrict__ trans,  // [U][N][N]
                               const float* __restrict__ emis,   // [U][N][S]
                               const float* __restrict__ initk,  // [U][N]
                               float* __restrict__ out)          // [B][T][U]
{
    __shared__ __bf16 AT[N_ * ROWP];   // phase 1: A^T[j][i] bf16; phase 2: alpha[b][i]
    __shared__ float BemS[N_][S_];
    __shared__ float IS[N_];

    const int bid = blockIdx.x;
    // u-swizzle: blocks on the same XCD (bid%8) get 32 consecutive u's, so the
    // 16 u's sharing a 64B output line are written from one XCD's L2.
    const int u = ((bid & 7) << 5) | (bid >> 3);
    const int tid = threadIdx.x;
    const int lane = tid & 63;
    const int w = tid >> 6;       // wave id = batch tile
    const int q = lane >> 4;      // quad-of-16 id
    const int l = lane & 15;

    // ---------------- prologue: softmaxes (one-time) ----------------
    if (tid < 64) {
        // transition row i=tid, softmax over j; store transposed AT[j][i] as bf16
        const float* rowp = trans + (u * N_ + tid) * N_;
        float v[N_];
        #pragma unroll
        for (int k = 0; k < 16; ++k) {
            floatx4 t4 = *(const floatx4*)(rowp + 4 * k);
            v[4*k] = t4.x; v[4*k+1] = t4.y; v[4*k+2] = t4.z; v[4*k+3] = t4.w;
        }
        float m = v[0];
        #pragma unroll
        for (int j = 1; j < N_; ++j) m = fmaxf(m, v[j]);
        float s = 0.f;
        #pragma unroll
        for (int j = 0; j < N_; ++j) { v[j] = __expf(v[j] - m); s += v[j]; }
        float inv = 1.0f / s;
        #pragma unroll
        for (int j = 0; j < N_; ++j) AT[j * ROWP + tid] = (__bf16)(v[j] * inv);
    } else if (tid < 128) {
        int n = tid - 64;
        floatx4 e4 = *(const floatx4*)(emis + (u * N_ + n) * S_);
        float m = fmaxf(fmaxf(e4.x, e4.y), fmaxf(e4.z, e4.w));
        float a = __expf(e4.x - m), b2 = __expf(e4.y - m);
        float c = __expf(e4.z - m), d = __expf(e4.w - m);
        float inv = 1.0f / (a + b2 + c + d);
        BemS[n][0] = a*inv; BemS[n][1] = b2*inv; BemS[n][2] = c*inv; BemS[n][3] = d*inv;
    } else if (tid < 192) {
        int j = tid - 128;
        float v = initk[u * N_ + j];
        float m = v;
        #pragma unroll
        for (int s = 1; s < 64; s <<= 1) m = fmaxf(m, __shfl_xor(m, s, 64));
        float e = __expf(v - m);
        float ssum = e;
        #pragma unroll
        for (int s = 1; s < 64; s <<= 1) ssum += __shfl_xor(ssum, s, 64);
        IS[j] = e / ssum;
    }
    __syncthreads();

    // ------------- gather persistent register state -------------
    // A-operand frag (16x16x32): lane holds Aop[m=16jt+l][k=32kt+8q+jj]
    //   = A[i=32kt+8q+jj][j=16jt+l]  (AT is A^T, row j, col i)
    bf16x8 afrag[4][2];
    #pragma unroll
    for (int jt = 0; jt < 4; ++jt)
        #pragma unroll
        for (int kt = 0; kt < 2; ++kt)
            afrag[jt][kt] = *(const bf16x8*)&AT[(16*jt + l) * ROWP + 32*kt + 8*q];

    // Per-lane emission rows + init values for this lane's 16 j's:
    // j = 16*jt + 4*q + r  (matches C/D layout row = 4q + reg)
    floatx4 Bemr[4][4];
    float Iv[4][4];
    #pragma unroll
    for (int jt = 0; jt < 4; ++jt)
        #pragma unroll
        for (int r = 0; r < 4; ++r) {
            int j = 16*jt + 4*q + r;
            Bemr[jt][r] = *(const floatx4*)&BemS[j][0];
            Iv[jt][r] = IS[j];
        }
    __syncthreads();   // AT is now reused as the alpha buffer (wave-private rows)

    __bf16* arow = &AT[(16*w + l) * ROWP];   // alpha[b][.] row for this lane's b
    const int b = 16*w + l;                  // C/D layout: col = lane&15 = batch
    const float* xin = xg + b * (T_ * S_);
    float* outp = out + (size_t)b * T_ * U_ + u;

    float ll = 0.f;
    bf16x8 bfrag[2];

    floatx4 x4 = *(const floatx4*)(xin);
    floatx4 xn = *(const floatx4*)(xin + S_);

    // Generic step tail: given R[jt][r] and E[jt][r], do fwd/Ssum/ll/normalize,
    // write next alpha (bf16) into the wave-private LDS rows.
    auto tail = [&](const float (&R)[4][4], const float (&Ev)[4][4], int t) {
        float fn[4][4];
        float ss = 0.f;
        #pragma unroll
        for (int jt = 0; jt < 4; ++jt)
            #pragma unroll
            for (int r = 0; r < 4; ++r) {
                float f = Ev[jt][r] * R[jt][r];
                fn[jt][r] = f;
                ss += f;
            }
        // sum over all 64 j: 15 in-lane adds (above) + across the 4 q-lanes
        ss += __shfl_xor(ss, 16, 64);
        ss += __shfl_xor(ss, 32, 64);
        ll += __logf(ss);
        if (q == 0) outp[t * U_] = ll;
        float rs = __builtin_amdgcn_rcpf(ss);
        #pragma unroll
        for (int jt = 0; jt < 4; ++jt) {
            bf16x4 a4;
            a4.x = (__bf16)(fn[jt][0] * rs);
            a4.y = (__bf16)(fn[jt][1] * rs);
            a4.z = (__bf16)(fn[jt][2] * rs);
            a4.w = (__bf16)(fn[jt][3] * rs);
            *(bf16x4*)&arow[16*jt + 4*q] = a4;   // 4 consecutive j -> ds_write_b64
        }
    };

    // B-operand frag: lane holds Bop[k=32kt+8q+jj][n=l] = alpha[b][i=32kt+8q+jj]
    auto loadb = [&]() {
        __asm__ volatile("s_waitcnt lgkmcnt(0)" ::: "memory");
        bfrag[0] = *(const bf16x8*)&arow[8*q];
        bfrag[1] = *(const bf16x8*)&arow[32 + 8*q];
    };

    // ---- t = 0: alpha=0, is_init=1 -> R = I ----
    {
        float Ev[4][4];
        #pragma unroll
        for (int jt = 0; jt < 4; ++jt)
            #pragma unroll
            for (int r = 0; r < 4; ++r) {
                floatx4 bm = Bemr[jt][r];
                Ev[jt][r] = fmaf(bm.x, x4.x, fmaf(bm.y, x4.y, fmaf(bm.z, x4.z, bm.w * x4.w)));
            }
        tail(Iv, Ev, 0);
        loadb();
    }

    // ---- t = 1 .. T-1 ----
    for (int t = 1; t < T_; ++t) {
        x4 = xn;
        int tn = (t + 1 < T_) ? t + 1 : t;
        xn = *(const floatx4*)(xin + tn * S_);   // prefetch next step's x

        // E first (independent of MFMA result -> overlaps MFMA latency)
        float Ev[4][4];
        #pragma unroll
        for (int jt = 0; jt < 4; ++jt)
            #pragma unroll
            for (int r = 0; r < 4; ++r) {
                floatx4 bm = Bemr[jt][r];
                Ev[jt][r] = fmaf(bm.x, x4.x, fmaf(bm.y, x4.y, fmaf(bm.z, x4.z, bm.w * x4.w)));
            }

        floatx4 acc[4];
        #pragma unroll
        for (int jt = 0; jt < 4; ++jt) { floatx4 z = {0.f, 0.f, 0.f, 0.f}; acc[jt] = z; }
        #pragma unroll
        for (int kt = 0; kt < 2; ++kt)
            #pragma unroll
            for (int jt = 0; jt < 4; ++jt)
                acc[jt] = __builtin_amdgcn_mfma_f32_16x16x32_bf16(
                              afrag[jt][kt], bfrag[kt], acc[jt], 0, 0, 0);

        float R[4][4];
        #pragma unroll
        for (int jt = 0; jt < 4; ++jt)
            #pragma unroll
            for (int r = 0; r < 4; ++r) R[jt][r] = acc[jt][r];

        tail(R, Ev, t);
        loadb();
    }
}

extern "C" void kernel_launch(void* const* d_in, const int* in_sizes, int n_in,
                              void* d_out, int out_size, void* d_ws, size_t ws_size,
                              hipStream_t stream) {
    const float* xg    = (const float*)d_in[0];  // inputs [B,T,S]
    const float* trans = (const float*)d_in[1];  // transition [U,N,N]
    const float* emis  = (const float*)d_in[2];  // emission [U,N,S]
    const float* initk = (const float*)d_in[3];  // init [U,N]
    float* out = (float*)d_out;
    hipLaunchKernelGGL(hmm_fwd_kernel, dim3(U_), dim3(256), 0, stream,
                       xg, trans, emis, initk, out);
}

// Round 2
// 496.019 us; speedup vs baseline: 1.1517x; 1.1517x over previous
//
#include <hip/hip_runtime.h>

// HMM forward scan, one workgroup per unit u.
//   U=256 units, N=64 states, S=4 symbols, B=64 batch, T=1024 steps.
// Wave w (of 4) owns batches b in [16w,16w+16); lane (q=lane>>4, l=lane&15)
// owns batch b=16w+l and 16 j-states.
//
// Key trick 1: MFMA m-tile jt computes rows j = sig(jt,m) = 32(jt>>1)+4(jt&1)
//   +8(m>>2)+(m&3). With this row permutation the C-layout accumulator values
//   a lane holds are EXACTLY the k-slices of its own next-step B-operand
//   fragment: bfrag[kt][j7] = g[2kt+(j7>>2)][j7&3]. Alpha hand-off = 16 local
//   bf16 converts. No LDS / shuffles / barriers in the T-loop.
// Key trick 2: deferred normalization. Feed unnormalized g_t = fwd_t to the
//   MFMA; fold rs=1/ss into next step's emission via x*rs (4 muls). The
//   ss-reduce/log/rcp path runs in parallel with the pack->MFMA chain.

#define U_ 256
#define N_ 64
#define S_ 4
#define B_ 64
#define T_ 1024
#define ROWP 72  // prologue LDS row stride (bf16 elems); 16B-aligned rows

typedef __attribute__((ext_vector_type(8))) __bf16 bf16x8;
typedef __attribute__((ext_vector_type(4))) float floatx4;

__device__ __forceinline__ int sig(int jt, int m) {
    return 32 * (jt >> 1) + 4 * (jt & 1) + 8 * (m >> 2) + (m & 3);
}

__launch_bounds__(256, 1)
__global__ void hmm_fwd_kernel(const float* __restrict__ xg,     // [B][T][S]
                               const float* __restrict__ trans,  // [U][N][N]
                               const float* __restrict__ emis,   // [U][N][S]
                               const float* __restrict__ initk,  // [U][N]
                               float* __restrict__ out)          // [B][T][U]
{
    __shared__ __bf16 AT[N_ * ROWP];   // A^T[j][i] bf16 (prologue only)
    __shared__ float BemS[N_][S_];
    __shared__ float IS[N_];

    const int bid = blockIdx.x;
    // u-swizzle: the 16 u's sharing a 64B output line live on one XCD.
    const int u = ((bid & 7) << 5) | (bid >> 3);
    const int tid = threadIdx.x;
    const int lane = tid & 63;
    const int w = tid >> 6;
    const int q = lane >> 4;
    const int l = lane & 15;

    // ---------------- prologue: softmaxes (one-time) ----------------
    if (tid < 64) {
        const float* rowp = trans + (u * N_ + tid) * N_;
        float v[N_];
        #pragma unroll
        for (int k = 0; k < 16; ++k) {
            floatx4 t4 = *(const floatx4*)(rowp + 4 * k);
            v[4*k] = t4.x; v[4*k+1] = t4.y; v[4*k+2] = t4.z; v[4*k+3] = t4.w;
        }
        float m = v[0];
        #pragma unroll
        for (int j = 1; j < N_; ++j) m = fmaxf(m, v[j]);
        float s = 0.f;
        #pragma unroll
        for (int j = 0; j < N_; ++j) { v[j] = __expf(v[j] - m); s += v[j]; }
        float inv = 1.0f / s;
        #pragma unroll
        for (int j = 0; j < N_; ++j) AT[j * ROWP + tid] = (__bf16)(v[j] * inv);
    } else if (tid < 128) {
        int n = tid - 64;
        floatx4 e4 = *(const floatx4*)(emis + (u * N_ + n) * S_);
        float m = fmaxf(fmaxf(e4.x, e4.y), fmaxf(e4.z, e4.w));
        float a = __expf(e4.x - m), b2 = __expf(e4.y - m);
        float c = __expf(e4.z - m), d = __expf(e4.w - m);
        float inv = 1.0f / (a + b2 + c + d);
        BemS[n][0] = a*inv; BemS[n][1] = b2*inv; BemS[n][2] = c*inv; BemS[n][3] = d*inv;
    } else if (tid < 192) {
        int j = tid - 128;
        float v = initk[u * N_ + j];
        float m = v;
        #pragma unroll
        for (int s = 1; s < 64; s <<= 1) m = fmaxf(m, __shfl_xor(m, s, 64));
        float e = __expf(v - m);
        float ssum = e;
        #pragma unroll
        for (int s = 1; s < 64; s <<= 1) ssum += __shfl_xor(ssum, s, 64);
        IS[j] = e / ssum;
    }
    __syncthreads();

    // ------------- persistent register state -------------
    // A-frag: lane (q,l) holds A_eff[m=l][k=32kt+8q+jj] = AT[sig(jt,l)][i]
    bf16x8 afrag[4][2];
    #pragma unroll
    for (int jt = 0; jt < 4; ++jt)
        #pragma unroll
        for (int kt = 0; kt < 2; ++kt)
            afrag[jt][kt] = *(const bf16x8*)&AT[sig(jt, l) * ROWP + 32*kt + 8*q];

    // Emission columns + init, permuted by sig: cell (jt,r) <-> j = sig(jt,4q+r)
    floatx4 Bcol[4][4];   // [c][jt][r]
    floatx4 Iv[4];
    #pragma unroll
    for (int jt = 0; jt < 4; ++jt) {
        #pragma unroll
        for (int r = 0; r < 4; ++r) {
            int j = sig(jt, 4*q + r);
            #pragma unroll
            for (int c = 0; c < 4; ++c) Bcol[c][jt][r] = BemS[j][c];
            Iv[jt][r] = IS[j];
        }
    }
    __syncthreads();

    const int b = 16*w + l;
    const float* xin = xg + b * (T_ * S_);
    float* outp = out + (size_t)b * T_ * U_ + u;

    floatx4 Ev[4], Rv[4];
    {
        floatx4 x0 = *(const floatx4*)xin;
        #pragma unroll
        for (int jt = 0; jt < 4; ++jt)
            Ev[jt] = Bcol[0][jt]*x0.x + Bcol[1][jt]*x0.y
                   + Bcol[2][jt]*x0.z + Bcol[3][jt]*x0.w;
        #pragma unroll
        for (int jt = 0; jt < 4; ++jt) Rv[jt] = Iv[jt];   // t=0: R = I
    }
    floatx4 xnext = *(const floatx4*)(xin + S_);   // x_1
    float ll = 0.f;

    for (int t = 0; t < T_; ++t) {
        // prefetch x_{t+2} (2 steps of slack)
        int tp = (t + 2 < T_) ? t + 2 : T_ - 1;
        floatx4 xpre = *(const floatx4*)(xin + tp * S_);

        // g = E (pre-scaled) * R   -- unnormalized fwd, == true fwd_t
        floatx4 gv[4];
        #pragma unroll
        for (int jt = 0; jt < 4; ++jt) gv[jt] = Ev[jt] * Rv[jt];

        // pack next B-operand fragment (local converts only)
        bf16x8 bf0, bf1;
        #pragma unroll
        for (int p = 0; p < 4; ++p) {
            bf0[p]     = (__bf16)gv[0][p];
            bf0[4 + p] = (__bf16)gv[1][p];
            bf1[p]     = (__bf16)gv[2][p];
            bf1[4 + p] = (__bf16)gv[3][p];
        }

        // ss = sum over all 64 j (runs in parallel with pack+MFMA)
        floatx4 s2 = (gv[0] + gv[1]) + (gv[2] + gv[3]);
        float ss = (s2.x + s2.y) + (s2.z + s2.w);
        ss += __shfl_xor(ss, 16, 64);
        ss += __shfl_xor(ss, 32, 64);
        ll += __logf(ss);
        if (q == 0) outp[t * U_] = ll;

        // next emission, with 1/ss folded into x (deferred normalization)
        float rs = __builtin_amdgcn_rcpf(ss);
        floatx4 xc = xnext;
        xnext = xpre;
        floatx4 xr = xc * rs;
        #pragma unroll
        for (int jt = 0; jt < 4; ++jt)
            Ev[jt] = Bcol[0][jt]*xr.x + Bcol[1][jt]*xr.y
                   + Bcol[2][jt]*xr.z + Bcol[3][jt]*xr.w;

        // R~_{t+1} = A^T g_t  (consumed next iteration)
        floatx4 z = {0.f, 0.f, 0.f, 0.f};
        #pragma unroll
        for (int jt = 0; jt < 4; ++jt) {
            floatx4 acc = __builtin_amdgcn_mfma_f32_16x16x32_bf16(
                              afrag[jt][0], bf0, z, 0, 0, 0);
            acc = __builtin_amdgcn_mfma_f32_16x16x32_bf16(
                              afrag[jt][1], bf1, acc, 0, 0, 0);
            Rv[jt] = acc;
        }
    }
}

extern "C" void kernel_launch(void* const* d_in, const int* in_sizes, int n_in,
                              void* d_out, int out_size, void* d_ws, size_t ws_size,
                              hipStream_t stream) {
    const float* xg    = (const float*)d_in[0];
    const float* trans = (const float*)d_in[1];
    const float* emis  = (const float*)d_in[2];
    const float* initk = (const float*)d_in[3];
    float* out = (float*)d_out;
    hipLaunchKernelGGL(hmm_fwd_kernel, dim3(U_), dim3(256), 0, stream,
                       xg, trans, emis, initk, out);
}

// Round 4
// 362.177 us; speedup vs baseline: 1.5773x; 1.3695x over previous
//
#include <hip/hip_runtime.h>

// HMM forward scan, one workgroup per unit u. U=256, N=64, S=4, B=64, T=1024.
// Wave w owns batches [16w,16w+16); lane (q=lane>>4,l=lane&15) owns batch
// b=16w+l and the 16 states j = sig(jt, 4q+r).
//
// sig() row permutation: each lane's MFMA C-layout accumulator values are
// exactly its own next-step B-operand k-slices -> no LDS/shuffle/barrier in
// the T-loop. (Verified R1/R2.)
//
// E via MFMA: E[j][b] = sum_{c<4} Bem[j][c] x[b][c] as 4 zero-padded
// 16x16x32 bf16 MFMAs (k<4 live, q==0 lanes). Removes the 64-VGPR Bcol that
// the compiler refused to keep resident (R2: VGPR=84 -> in-loop LDS remat).
//
// Normalization: 1-step-lag scale folded into x: bfragE for step t+1 packed
// with rs_{t-1}. Magnitude recurrence m_{t+1} = c_{t+1} m_t / m_{t-1} ->
// char poly z^2-z+1, roots ON unit circle: bounded oscillation (stable; the
// R3 NaN came from kappa=rs_{t-2}, z^3-z^2+1, |z|=1.155 -> overflow).
// Exact ll: ll_t = ll_{t-1} + sigma_t - sigma_{t-1} + sigma_{t-2},
// sigma=log(m). Reduce/log/rcp get a full step of slack.

#define U_ 256
#define N_ 64
#define S_ 4
#define B_ 64
#define T_ 1024
#define ROWP 72

typedef __attribute__((ext_vector_type(8))) __bf16 bf16x8;
typedef __attribute__((ext_vector_type(4))) float floatx4;

__device__ __forceinline__ int sig(int jt, int m) {
    return 32 * (jt >> 1) + 4 * (jt & 1) + 8 * (m >> 2) + (m & 3);
}

__launch_bounds__(256, 1)
__global__ void hmm_fwd_kernel(const float* __restrict__ xg,     // [B][T][S]
                               const float* __restrict__ trans,  // [U][N][N]
                               const float* __restrict__ emis,   // [U][N][S]
                               const float* __restrict__ initk,  // [U][N]
                               float* __restrict__ out)          // [B][T][U]
{
    __shared__ __bf16 AT[N_ * ROWP];
    __shared__ float BemS[N_][S_];
    __shared__ float IS[N_];

    const int bid = blockIdx.x;
    const int u = ((bid & 7) << 5) | (bid >> 3);   // XCD-aware u swizzle
    const int tid = threadIdx.x;
    const int lane = tid & 63;
    const int w = tid >> 6;
    const int q = lane >> 4;
    const int l = lane & 15;

    // ---------------- prologue: softmaxes (one-time) ----------------
    if (tid < 64) {
        const float* rowp = trans + (u * N_ + tid) * N_;
        float v[N_];
        #pragma unroll
        for (int k = 0; k < 16; ++k) {
            floatx4 t4 = *(const floatx4*)(rowp + 4 * k);
            v[4*k] = t4.x; v[4*k+1] = t4.y; v[4*k+2] = t4.z; v[4*k+3] = t4.w;
        }
        float m = v[0];
        #pragma unroll
        for (int j = 1; j < N_; ++j) m = fmaxf(m, v[j]);
        float s = 0.f;
        #pragma unroll
        for (int j = 0; j < N_; ++j) { v[j] = __expf(v[j] - m); s += v[j]; }
        float inv = 1.0f / s;
        #pragma unroll
        for (int j = 0; j < N_; ++j) AT[j * ROWP + tid] = (__bf16)(v[j] * inv);
    } else if (tid < 128) {
        int n = tid - 64;
        floatx4 e4 = *(const floatx4*)(emis + (u * N_ + n) * S_);
        float m = fmaxf(fmaxf(e4.x, e4.y), fmaxf(e4.z, e4.w));
        float a = __expf(e4.x - m), b2 = __expf(e4.y - m);
        float c = __expf(e4.z - m), d = __expf(e4.w - m);
        float inv = 1.0f / (a + b2 + c + d);
        BemS[n][0] = a*inv; BemS[n][1] = b2*inv; BemS[n][2] = c*inv; BemS[n][3] = d*inv;
    } else if (tid < 192) {
        int j = tid - 128;
        float v = initk[u * N_ + j];
        float m = v;
        #pragma unroll
        for (int s = 1; s < 64; s <<= 1) m = fmaxf(m, __shfl_xor(m, s, 64));
        float e = __expf(v - m);
        float ssum = e;
        #pragma unroll
        for (int s = 1; s < 64; s <<= 1) ssum += __shfl_xor(ssum, s, 64);
        IS[j] = e / ssum;
    }
    __syncthreads();

    // ------------- persistent register state -------------
    // Transition A-frag: lane holds A_eff[m=l][k=8q+jj] per (jt,kt)
    bf16x8 afrag[4][2];
    #pragma unroll
    for (int jt = 0; jt < 4; ++jt)
        #pragma unroll
        for (int kt = 0; kt < 2; ++kt)
            afrag[jt][kt] = *(const bf16x8*)&AT[sig(jt, l) * ROWP + 32*kt + 8*q];

    // Emission A-frag: A_E[m][k] = Bem[sig(jt,m)][k] for k<4, else 0.
    bf16x8 afragE[4];
    #pragma unroll
    for (int jt = 0; jt < 4; ++jt) {
        #pragma unroll
        for (int p = 0; p < 8; ++p) afragE[jt][p] = (__bf16)0.f;
        if (q == 0) {
            #pragma unroll
            for (int c = 0; c < 4; ++c)
                afragE[jt][c] = (__bf16)BemS[sig(jt, l)][c];
        }
    }

    // Rv init = I (t=0: R = I), in sig-permuted C layout
    floatx4 Rv[4];
    #pragma unroll
    for (int jt = 0; jt < 4; ++jt)
        #pragma unroll
        for (int r = 0; r < 4; ++r) Rv[jt][r] = IS[sig(jt, 4*q + r)];

    // Compiler barrier: LDS-sourced values above must stay in VGPRs (no
    // in-loop rematerialization of LDS reads). Occupancy is grid-pinned at
    // 1 wave/SIMD so ~256 VGPRs are available.
    __asm__ volatile("" ::: "memory");

    const int b = 16*w + l;
    const float* xin = xg + b * (T_ * S_);
    float* outp = out + (size_t)b * T_ * U_ + u;

    const floatx4 z = {0.f, 0.f, 0.f, 0.f};
    floatx4 Ev[4], gv[4];
    float ll = 0.f, sp1 = 0.f, sp2 = 0.f, rsA = 1.0f;

    // ---------------- pipeline fill ----------------
    floatx4 x0 = *(const floatx4*)xin;
    floatx4 xA = *(const floatx4*)(xin + S_);       // x_1
    floatx4 xB = *(const floatx4*)(xin + 2 * S_);   // x_2

    {
        // Ev_0 via E-MFMA (kappa_0 = 1)
        bf16x8 be;
        #pragma unroll
        for (int p = 0; p < 8; ++p) be[p] = (__bf16)0.f;
        if (q == 0) {
            be[0] = (__bf16)x0.x; be[1] = (__bf16)x0.y;
            be[2] = (__bf16)x0.z; be[3] = (__bf16)x0.w;
        }
        #pragma unroll
        for (int jt = 0; jt < 4; ++jt)
            Ev[jt] = __builtin_amdgcn_mfma_f32_16x16x32_bf16(afragE[jt], be, z, 0, 0, 0);
    }

    // ---------------- t = 0 .. T-1 ----------------
    #pragma unroll 2
    for (int t = 0; t < T_; ++t) {
        // gv_t = Ev_t o Rv_t
        #pragma unroll
        for (int jt = 0; jt < 4; ++jt) gv[jt] = Ev[jt] * Rv[jt];

        // pack b_t = bf16(gv_t)  (scale already carried inside Ev)
        bf16x8 bf0, bf1;
        #pragma unroll
        for (int p = 0; p < 4; ++p) {
            bf0[p]     = (__bf16)gv[0][p];
            bf0[4 + p] = (__bf16)gv[1][p];
            bf1[p]     = (__bf16)gv[2][p];
            bf1[4 + p] = (__bf16)gv[3][p];
        }

        // R_{t+1} = A^T b_t  (overwrites Rv; gv already extracted)
        #pragma unroll
        for (int jt = 0; jt < 4; ++jt) {
            floatx4 acc = __builtin_amdgcn_mfma_f32_16x16x32_bf16(afrag[jt][0], bf0, z, 0, 0, 0);
            Rv[jt] = __builtin_amdgcn_mfma_f32_16x16x32_bf16(afrag[jt][1], bf1, acc, 0, 0, 0);
        }

        // m_t reduce: in-lane + 3 parallel shfls (same l, all 4 q -> full j-sum)
        floatx4 s4 = (gv[0] + gv[1]) + (gv[2] + gv[3]);
        float p0 = (s4.x + s4.y) + (s4.z + s4.w);
        float a16 = __shfl_xor(p0, 16, 64);
        float a32 = __shfl_xor(p0, 32, 64);
        float a48 = __shfl_xor(p0, 48, 64);
        float ss = (p0 + a16) + (a32 + a48);
        float sg = __logf(ss);
        float rs = __builtin_amdgcn_rcpf(ss);

        // ll_t = ll_{t-1} + sigma_t - sigma_{t-1} + sigma_{t-2}
        ll += sg - sp1 + sp2;
        if (q == 0) outp[t * U_] = ll;
        sp2 = sp1; sp1 = sg;

        // Ev_{t+1} via E-MFMA, x_{t+1} scaled by rs_{t-1} (1-step-lag kappa;
        // rsA not yet updated -> still rs_{t-1})
        bf16x8 be;
        #pragma unroll
        for (int p = 0; p < 8; ++p) be[p] = (__bf16)0.f;
        if (q == 0) {
            floatx4 xs = xA * rsA;
            be[0] = (__bf16)xs.x; be[1] = (__bf16)xs.y;
            be[2] = (__bf16)xs.z; be[3] = (__bf16)xs.w;
        }
        #pragma unroll
        for (int jt = 0; jt < 4; ++jt)
            Ev[jt] = __builtin_amdgcn_mfma_f32_16x16x32_bf16(afragE[jt], be, z, 0, 0, 0);
        rsA = rs;

        // x ring: xA <- x_{t+2}, xB <- x_{t+3} (2 iterations of load slack)
        xA = xB;
        int tp = (t + 3 < T_) ? t + 3 : T_ - 1;
        xB = *(const floatx4*)(xin + tp * S_);
    }
}

extern "C" void kernel_launch(void* const* d_in, const int* in_sizes, int n_in,
                              void* d_out, int out_size, void* d_ws, size_t ws_size,
                              hipStream_t stream) {
    const float* xg    = (const float*)d_in[0];
    const float* trans = (const float*)d_in[1];
    const float* emis  = (const float*)d_in[2];
    const float* initk = (const float*)d_in[3];
    float* out = (float*)d_out;
    hipLaunchKernelGGL(hmm_fwd_kernel, dim3(U_), dim3(256), 0, stream,
                       xg, trans, emis, initk, out);
}